// Round 5
// baseline (261.321 us; speedup 1.0000x reference)
//
#include <hip/hip_runtime.h>
#include <hip/hip_bf16.h>

// QuantLinear: out[t,o] = scale[o] * sum_k x[t,k]*q[o,k] + bias[o]
// M=32, N=11008, K=4096. x/scales/bias/out fp32, qweight int32 (int8 vals).
// 180.4 MB weight stream -> ~29 us floor.
// Round-5: K-loop barriers REMOVED (chunks are wave-private; __syncthreads
// was pure overhead). Per-wave ping-pong 4 KB chunks + explicit
// s_waitcnt vmcnt(4): next chunk's DMA stays in flight during compute
// (AITER-style never-vmcnt(0) pipeline). Worst case (compiler demotes to
// vmcnt(0)): serial-per-wave with no barrier — still better than r4.

constexpr int IN_F   = 4096;
constexpr int OUT_F  = 11008;
constexpr int KSLICE = 512;             // per-wave K range (8-way K-split)
constexpr int CK     = 64;              // ints per row per chunk (256 B)
constexpr int NCHUNK = KSLICE / CK;     // 8 chunks of 4 KB

typedef short bf16x8 __attribute__((ext_vector_type(8)));  // 8 bf16
typedef float f32x4  __attribute__((ext_vector_type(4)));

union B8 { bf16x8 v; unsigned u[4]; };

// [hi16(lo), hi16(hi)] -> bf16 pair (truncate). Exact for int8 values.
__device__ __forceinline__ unsigned pack2f(float lo, float hi) {
    return __builtin_amdgcn_perm(__float_as_uint(hi),
                                 __float_as_uint(lo),
                                 0x07060302u);
}

// x fp32 -> bf16 (truncate) into workspace. 131072 elems.
__global__ __launch_bounds__(256)
void xconv_kernel(const float* __restrict__ x, unsigned* __restrict__ xb) {
    const int i = (blockIdx.x * 256 + threadIdx.x) * 4;
    float4 v = *reinterpret_cast<const float4*>(x + i);
    xb[i / 2]     = pack2f(v.x, v.y);
    xb[i / 2 + 1] = pack2f(v.z, v.w);
}

__global__ __launch_bounds__(512, 4)   // 2 blocks/CU; LDS 78 KB/block
void qlin_kernel(const unsigned short* __restrict__ xb,  // bf16 bits [32][4096]
                 const int* __restrict__ w,              // int32 [11008][4096]
                 const float* __restrict__ scales,       // [11008]
                 const float* __restrict__ bias,         // [11008]
                 float* __restrict__ out)                // [32][11008]
{
    __shared__ int   wbuf[8][2][CK * 16];   // [wave][pingpong][4 KB]
    __shared__ float red[7][2][4][64];      // cross-wave reduction

    const int lane = threadIdx.x & 63;
    const int wv   = threadIdx.x >> 6;   // 0..7: K-split across 8 waves
    const int r    = lane & 15;
    const int q    = lane >> 4;
    const int swz  = r & 7;

    const int n0 = blockIdx.x << 4;      // 688 blocks x 16 output rows
    const int kb = wv * KSLICE;

    f32x4 acc0 = {0.f, 0.f, 0.f, 0.f};   // tokens 0..15
    f32x4 acc1 = {0.f, 0.f, 0.f, 0.f};   // tokens 16..31

    // A-frags from global (L2-resident bf16 x)
    const unsigned short* xp0 = xb + r * IN_F + kb + q * 8;
    const unsigned short* xp1 = xp0 + 16 * IN_F;

    // Issue one 4 KB chunk: 4 DMA instrs of 1 KB. Instr j covers rows
    // 4j..4j+3 (256 B each): lane l -> LDS byte j*1024 + l*16 = row
    // 4j+(l>>4), slot l&15. Source swizzled so slot s holds group s^(row&7).
    auto issue_dma = [&](int c, int buf) {
        const int kc = kb + c * CK;
        #pragma unroll
        for (int j = 0; j < 4; ++j) {
            const int rj = 4 * j + (lane >> 4);
            const int gj = (lane & 15) ^ (rj & 7);
            const int* src = w + (size_t)(n0 + rj) * IN_F + kc + 4 * gj;
            __builtin_amdgcn_global_load_lds(
                (const __attribute__((address_space(1))) void*)src,
                (__attribute__((address_space(3))) void*)&wbuf[wv][buf][j * 256],
                16, 0, 0);
        }
    };

    auto compute = [&](int c, const bf16x8* af0, const bf16x8* af1) {
        const int4* lsp =
            reinterpret_cast<const int4*>(&wbuf[wv][c & 1][0]) + r * 16;
        #pragma unroll
        for (int i = 0; i < 2; ++i) {
            const int G0 = i * 8 + q * 2;
            int4 qa = lsp[G0 ^ swz];
            int4 qb = lsp[(G0 + 1) ^ swz];
            B8 bb;
            bb.u[0] = pack2f((float)qa.x, (float)qa.y);
            bb.u[1] = pack2f((float)qa.z, (float)qa.w);
            bb.u[2] = pack2f((float)qb.x, (float)qb.y);
            bb.u[3] = pack2f((float)qb.z, (float)qb.w);
            acc0 = __builtin_amdgcn_mfma_f32_16x16x32_bf16(af0[i], bb.v, acc0, 0, 0, 0);
            acc1 = __builtin_amdgcn_mfma_f32_16x16x32_bf16(af1[i], bb.v, acc1, 0, 0, 0);
        }
    };

    issue_dma(0, 0);
    for (int c = 0; c < NCHUNK - 1; ++c) {
        bf16x8 af0[2], af1[2];
        #pragma unroll
        for (int i = 0; i < 2; ++i) {
            af0[i] = *reinterpret_cast<const bf16x8*>(xp0 + c * CK + i * 32);
            af1[i] = *reinterpret_cast<const bf16x8*>(xp1 + c * CK + i * 32);
        }
        issue_dma(c + 1, (c + 1) & 1);
        // vmcnt(4): chunk c's DMA + A-loads(c) done; chunk c+1 in flight.
        __builtin_amdgcn_s_waitcnt(0x0F74);
        compute(c, af0, af1);
    }
    {
        const int c = NCHUNK - 1;
        bf16x8 af0[2], af1[2];
        #pragma unroll
        for (int i = 0; i < 2; ++i) {
            af0[i] = *reinterpret_cast<const bf16x8*>(xp0 + c * CK + i * 32);
            af1[i] = *reinterpret_cast<const bf16x8*>(xp1 + c * CK + i * 32);
        }
        __builtin_amdgcn_s_waitcnt(0x0F70);   // vmcnt(0)
        compute(c, af0, af1);
    }

    // Cross-wave K reduction (the only barrier in the kernel).
    if (wv > 0) {
        #pragma unroll
        for (int i = 0; i < 4; ++i) {
            red[wv - 1][0][i][lane] = acc0[i];
            red[wv - 1][1][i][lane] = acc1[i];
        }
    }
    __syncthreads();
    if (wv == 0) {
        #pragma unroll
        for (int j = 0; j < 7; ++j) {
            #pragma unroll
            for (int i = 0; i < 4; ++i) {
                acc0[i] += red[j][0][i][lane];
                acc1[i] += red[j][1][i][lane];
            }
        }
        // C/D layout (m89/m91): col n = lane&15, row m = (lane>>4)*4 + reg
        const int n = n0 + r;
        const float s = scales[n];
        const float b = bias[n];
        #pragma unroll
        for (int i = 0; i < 4; ++i) {
            out[(q * 4 + i) * OUT_F + n]      = acc0[i] * s + b;
            out[(16 + q * 4 + i) * OUT_F + n] = acc1[i] * s + b;
        }
    }
}

extern "C" void kernel_launch(void* const* d_in, const int* in_sizes, int n_in,
                              void* d_out, int out_size, void* d_ws, size_t ws_size,
                              hipStream_t stream) {
    const float* x      = (const float*)d_in[0];
    const int*   w      = (const int*)d_in[1];
    const float* scales = (const float*)d_in[2];
    const float* bias   = (const float*)d_in[3];
    float*       out    = (float*)d_out;
    unsigned*    xb     = (unsigned*)d_ws;   // bf16 x, 256 KB

    xconv_kernel<<<dim3(32 * IN_F / (256 * 4)), dim3(256), 0, stream>>>(x, xb);
    qlin_kernel<<<dim3(OUT_F / 16), dim3(512), 0, stream>>>(
        (const unsigned short*)xb, w, scales, bias, out);
}

// Round 6
// 254.510 us; speedup vs baseline: 1.0268x; 1.0268x over previous
//
#include <hip/hip_runtime.h>
#include <hip/hip_bf16.h>

// QuantLinear: out[t,o] = scale[o] * sum_k x[t,k]*q[o,k] + bias[o]
// M=32, N=11008, K=4096. x/scales/bias/out fp32, qweight int32 (int8 vals).
// 180.4 MB weight stream -> ~27-29 us floor.
// Round-6: r4's exact geometry (8 KB wave-private chunks, 512 B runs/row)
// with K-loop __syncthreads REMOVED — wave-local s_waitcnt vmcnt(0) instead
// (mechanism correctness proven in r5). Single-variable test: barrier
// coupling vs DRAM-run-length as the r4/r5 differentiator.

constexpr int IN_F   = 4096;
constexpr int OUT_F  = 11008;
constexpr int KSLICE = 512;            // per-wave K range (8-way K-split)
constexpr int CK     = 128;            // K ints per chunk (512 B per row)

typedef short bf16x8 __attribute__((ext_vector_type(8)));  // 8 bf16
typedef float f32x4  __attribute__((ext_vector_type(4)));

union B8 { bf16x8 v; unsigned u[4]; };

// [hi16(lo), hi16(hi)] -> bf16 pair (truncate). Exact for int8 values.
__device__ __forceinline__ unsigned pack2f(float lo, float hi) {
    return __builtin_amdgcn_perm(__float_as_uint(hi),
                                 __float_as_uint(lo),
                                 0x07060302u);
}

// x fp32 -> bf16 (truncate) into workspace. 131072 elems.
__global__ __launch_bounds__(256)
void xconv_kernel(const float* __restrict__ x, unsigned* __restrict__ xb) {
    const int i = (blockIdx.x * 256 + threadIdx.x) * 4;
    float4 v = *reinterpret_cast<const float4*>(x + i);
    xb[i / 2]     = pack2f(v.x, v.y);
    xb[i / 2 + 1] = pack2f(v.z, v.w);
}

__global__ __launch_bounds__(512, 4)   // 2 blocks/CU; LDS 78 KB/block
void qlin_kernel(const unsigned short* __restrict__ xb,  // bf16 bits [32][4096]
                 const int* __restrict__ w,              // int32 [11008][4096]
                 const float* __restrict__ scales,       // [11008]
                 const float* __restrict__ bias,         // [11008]
                 float* __restrict__ out)                // [32][11008]
{
    __shared__ int   wbuf[8][CK * 16];        // 8 waves x 8 KB weight chunk
    __shared__ float red[7][2][4][64];        // cross-wave reduction

    const int lane = threadIdx.x & 63;
    const int wv   = threadIdx.x >> 6;   // 0..7: K-split across 8 waves
    const int r    = lane & 15;
    const int q    = lane >> 4;
    const int swz  = r & 7;

    const int n0 = blockIdx.x << 4;      // 688 blocks x 16 output rows
    const int kb = wv * KSLICE;

    f32x4 acc0 = {0.f, 0.f, 0.f, 0.f};   // tokens 0..15
    f32x4 acc1 = {0.f, 0.f, 0.f, 0.f};   // tokens 16..31

    // A-frags from global (L2-resident bf16 x)
    const unsigned short* xp0 = xb + r * IN_F + kb + q * 8;
    const unsigned short* xp1 = xp0 + 16 * IN_F;

    const int4* lsp = reinterpret_cast<const int4*>(&wbuf[wv][0]) + r * 32;

    for (int c = 0; c < KSLICE / CK; ++c) {
        const int kc = kb + c * CK;
        // Ordering fence: all ds_reads of the previous chunk retired before
        // the DMA below overwrites the buffer. Zero-cost at runtime (the
        // reads' data was already consumed by the MFMAs).
        __builtin_amdgcn_s_waitcnt(0xC07F);   // lgkmcnt(0)

        // Weight DMA: 8 x 1KB dense instructions, 512 B runs per row.
        // Instr j covers rows 2j,2j+1: lane l -> LDS byte j*1024 + l*16 =
        // row 2j+(l>>5), slot l&31. Source swizzled: slot s holds group
        // g = s ^ (row&7)  (2-way-free LDS bank spread).
        #pragma unroll
        for (int j = 0; j < 8; ++j) {
            const int rj = 2 * j + (lane >> 5);
            const int gj = (lane & 31) ^ (rj & 7);
            const int* src = w + (size_t)(n0 + rj) * IN_F + kc + 4 * gj;
            __builtin_amdgcn_global_load_lds(
                (const __attribute__((address_space(1))) void*)src,
                (__attribute__((address_space(3))) void*)&wbuf[wv][j * 256],
                16, 0, 0);
        }
        // A-frag prefetch for this chunk (L2-resident, overlaps DMA drain).
        bf16x8 af0[4], af1[4];
        #pragma unroll
        for (int i = 0; i < 4; ++i) {
            af0[i] = *reinterpret_cast<const bf16x8*>(xp0 + c * CK + i * 32);
            af1[i] = *reinterpret_cast<const bf16x8*>(xp1 + c * CK + i * 32);
        }
        // Wave-local drain: DMA chunk + A-loads complete. NO barrier —
        // the 16 waves/CU slip independently.
        __builtin_amdgcn_s_waitcnt(0x0F70);   // vmcnt(0)

        #pragma unroll
        for (int i = 0; i < 4; ++i) {
            const int G0 = i * 8 + q * 2;          // 16B k-group index
            int4 qa = lsp[G0 ^ swz];
            int4 qb = lsp[(G0 + 1) ^ swz];
            B8 bb;
            bb.u[0] = pack2f((float)qa.x, (float)qa.y);
            bb.u[1] = pack2f((float)qa.z, (float)qa.w);
            bb.u[2] = pack2f((float)qb.x, (float)qb.y);
            bb.u[3] = pack2f((float)qb.z, (float)qb.w);
            acc0 = __builtin_amdgcn_mfma_f32_16x16x32_bf16(af0[i], bb.v, acc0, 0, 0, 0);
            acc1 = __builtin_amdgcn_mfma_f32_16x16x32_bf16(af1[i], bb.v, acc1, 0, 0, 0);
        }
    }

    // Cross-wave K reduction (the only barrier in the kernel).
    if (wv > 0) {
        #pragma unroll
        for (int i = 0; i < 4; ++i) {
            red[wv - 1][0][i][lane] = acc0[i];
            red[wv - 1][1][i][lane] = acc1[i];
        }
    }
    __syncthreads();
    if (wv == 0) {
        #pragma unroll
        for (int j = 0; j < 7; ++j) {
            #pragma unroll
            for (int i = 0; i < 4; ++i) {
                acc0[i] += red[j][0][i][lane];
                acc1[i] += red[j][1][i][lane];
            }
        }
        // C/D layout (m89/m91): col n = lane&15, row m = (lane>>4)*4 + reg
        const int n = n0 + r;
        const float s = scales[n];
        const float b = bias[n];
        #pragma unroll
        for (int i = 0; i < 4; ++i) {
            out[(q * 4 + i) * OUT_F + n]      = acc0[i] * s + b;
            out[(16 + q * 4 + i) * OUT_F + n] = acc1[i] * s + b;
        }
    }
}

extern "C" void kernel_launch(void* const* d_in, const int* in_sizes, int n_in,
                              void* d_out, int out_size, void* d_ws, size_t ws_size,
                              hipStream_t stream) {
    const float* x      = (const float*)d_in[0];
    const int*   w      = (const int*)d_in[1];
    const float* scales = (const float*)d_in[2];
    const float* bias   = (const float*)d_in[3];
    float*       out    = (float*)d_out;
    unsigned*    xb     = (unsigned*)d_ws;   // bf16 x, 256 KB

    xconv_kernel<<<dim3(32 * IN_F / (256 * 4)), dim3(256), 0, stream>>>(x, xb);
    qlin_kernel<<<dim3(OUT_F / 16), dim3(512), 0, stream>>>(
        (const unsigned short*)xb, w, scales, bias, out);
}